// Round 5
// baseline (308.513 us; speedup 1.0000x reference)
//
#include <hip/hip_runtime.h>

#define CI 32
#define CO 32

constexpr float INV_S = 1.0f / 256.0f;
constexpr float THETA = 6.28318530717958647692f / 256.0f;

typedef float f32x16 __attribute__((ext_vector_type(16)));

// Wave-uniform 64B scalar load (broadcast on the scalar pipe, zero LDS/VALU).
// volatile: pin program order so the scheduler can't cluster-hoist 512-bit
// results and blow SGPR regalloc.
__device__ __forceinline__ f32x16 sload16(const float* p) {
  f32x16 r;
  asm volatile("s_load_dwordx16 %0, %1, 0x0\n\ts_waitcnt lgkmcnt(0)"
               : "=&s"(r) : "s"(p));
  return r;
}

// Two 64B scalar loads issued back-to-back, one wait. Offset between the two
// is a compile-time byte immediate (21-bit signed field on SMEM).
__device__ __forceinline__ void sload2x16_64(const float* p, f32x16& a, f32x16& b) {
  asm volatile("s_load_dwordx16 %0, %2, 0x0\n\t"
               "s_load_dwordx16 %1, %2, 0x40\n\t"
               "s_waitcnt lgkmcnt(0)"
               : "=&s"(a), "=&s"(b) : "s"(p));
}

__device__ __forceinline__ void sload2x16_16k(const float* p, f32x16& a, f32x16& b) {
  asm volatile("s_load_dwordx16 %0, %2, 0x0\n\t"
               "s_load_dwordx16 %1, %2, 0x4000\n\t"
               "s_waitcnt lgkmcnt(0)"
               : "=&s"(a), "=&s"(b) : "s"(p));
}

// -------------------------------------------------------------------------
// K0: trig tables in ws.
//  TC[n][k] = cos(2pi n k/256), TS[n][k] = sin   (TS = TC + 0x4000 bytes!)
//  TP[k][n] = cos+sin, TM[k][n] = cos-sin        (transposed, per-lane reads)
// -------------------------------------------------------------------------
__global__ void k_tab(float* __restrict__ TCb, float* __restrict__ TSb,
                      float* __restrict__ TPb, float* __restrict__ TMb) {
  const int t = threadIdx.x;  // n
  #pragma unroll
  for (int k = 0; k < 16; ++k) {
    float s, c;
    sincosf(THETA * (float)((k * t) & 255), &s, &c);
    TCb[t * 16 + k] = c;
    TSb[t * 16 + k] = s;
    TPb[k * 256 + t] = c + s;
    TMb[k * 256 + t] = c - s;
  }
}

// -------------------------------------------------------------------------
// K1: truncated forward DHT, one block per (b,i) image.
// Stage 1 contracts n1 with row-pair symmetry; trig rows come in via SGPRs.
// Stage 2 contracts n2 with b128-batched LDS reads + per-lane VMEM tables.
// -------------------------------------------------------------------------
__global__ __launch_bounds__(256, 2) void k_fwd(const float* __restrict__ x,
                                                const float* __restrict__ TCb,
                                                const float* __restrict__ TPb,
                                                const float* __restrict__ TMb,
                                                float* __restrict__ xh) {
  __shared__ __align__(16) float C1[16][260];  // +4 pad: k1-rows on distinct banks
  __shared__ __align__(16) float S1[16][260];
  const int t = threadIdx.x;
  const float* __restrict__ xp = x + (size_t)blockIdx.x * 65536 + t;

  float aC[16], aS[16];
  {  // rows 0 and 128: sin=0; cos row0 = 1, cos row128 = (-1)^k
    float x0 = xp[0];
    float xm = xp[128 * 256];
    float e = x0 + xm, o = x0 - xm;
    #pragma unroll
    for (int k = 0; k < 16; ++k) { aC[k] = (k & 1) ? o : e; aS[k] = 0.f; }
  }

  // paired rows (n, 256-n), n = 1..120 in chunks of 8 (16 loads in flight)
  for (int base = 1; base + 8 <= 121; base += 8) {
    float xlo[8], xhi[8];
    #pragma unroll
    for (int j = 0; j < 8; ++j) {
      xlo[j] = xp[(base + j) * 256];
      xhi[j] = xp[(256 - base - j) * 256];
    }
    #pragma unroll
    for (int j = 0; j < 8; ++j) {
      const int n = base + j;
      f32x16 tc, ts;
      sload2x16_16k(TCb + n * 16, tc, ts);  // ts row lives at +0x4000 bytes
      float es = xlo[j] + xhi[j];
      float ds = xlo[j] - xhi[j];
      #pragma unroll
      for (int k = 0; k < 16; ++k) {
        aC[k] = fmaf(es, tc[k], aC[k]);
        aS[k] = fmaf(ds, ts[k], aS[k]);
      }
    }
  }
  // tail rows 121..127
  for (int n = 121; n < 128; ++n) {
    float lo = xp[n * 256];
    float hi = xp[(256 - n) * 256];
    f32x16 tc, ts;
    sload2x16_16k(TCb + n * 16, tc, ts);
    float es = lo + hi, ds = lo - hi;
    #pragma unroll
    for (int k = 0; k < 16; ++k) {
      aC[k] = fmaf(es, tc[k], aC[k]);
      aS[k] = fmaf(ds, ts[k], aS[k]);
    }
  }

  #pragma unroll
  for (int k = 0; k < 16; ++k) { C1[k][t] = aC[k]; S1[k][t] = aS[k]; }
  __syncthreads();

  // stage 2: Xh[k1,k2] = (1/256) sum_n2 [ C1*(c+s) + S1*(c-s) ]
  const int k1 = t >> 4, k2 = t & 15;
  const float* __restrict__ tp = TPb + k2 * 256;  // L1-resident (16 KB)
  const float* __restrict__ tm = TMb + k2 * 256;
  float acc = 0.f;
  #pragma unroll 2
  for (int n2 = 0; n2 < 256; n2 += 4) {
    const float4 c4 = *(const float4*)&C1[k1][n2];
    const float4 s4 = *(const float4*)&S1[k1][n2];
    const float4 p4 = *(const float4*)&tp[n2];
    const float4 m4 = *(const float4*)&tm[n2];
    acc = fmaf(c4.x, p4.x, acc); acc = fmaf(s4.x, m4.x, acc);
    acc = fmaf(c4.y, p4.y, acc); acc = fmaf(s4.y, m4.y, acc);
    acc = fmaf(c4.z, p4.z, acc); acc = fmaf(s4.z, m4.z, acc);
    acc = fmaf(c4.w, p4.w, acc); acc = fmaf(s4.w, m4.w, acc);
  }
  xh[(size_t)blockIdx.x * 256 + t] = acc * INV_S;
}

// -------------------------------------------------------------------------
// K2: mode mix + inverse-DHT stage A, one block per (b,o).
//   res = 0.5 * sum_i [ x*(w+wn) + xn*(w-wn) ],  n-index = (-k) mod 16
//   W[n1][k2]   = sum_k1 res*cos(k1 n1)   (rows 0..128 only; U[256-n]=U[n])
//   W[n1][16+k2]= sum_k1 res*sin(k1 n1)   (V[256-n]=-V[n])
// -------------------------------------------------------------------------
__global__ __launch_bounds__(256, 2) void k_mid(const float* __restrict__ xh,
                                                const float* __restrict__ w,
                                                float* __restrict__ Wout) {
  __shared__ float xs[CI][256];
  __shared__ __align__(16) float rsm[256];
  const int t = threadIdx.x;
  const int b = blockIdx.x >> 5;
  const int o = blockIdx.x & 31;

  #pragma unroll 8
  for (int i = 0; i < CI; ++i)
    xs[i][t] = xh[(size_t)(b * CI + i) * 256 + t];
  __syncthreads();

  const int k1 = t >> 4, k2 = t & 15;
  const int tn = (((16 - k1) & 15) << 4) | ((16 - k2) & 15);
  float acc = 0.f;
  #pragma unroll 8
  for (int i = 0; i < CI; ++i) {
    const float* __restrict__ wrow = w + (size_t)(i * CO + o) * 256;
    float wp = wrow[t];
    float wn = wrow[tn];  // gather within 1 KB row: L1/L2 hit
    float xv = xs[i][t];
    float xnv = xs[i][tn];
    acc = fmaf(xv, wp + wn, acc);
    acc = fmaf(xnv, wp - wn, acc);
  }
  rsm[t] = 0.5f * acc;
  __syncthreads();

  if (t <= 128) {  // thread t = output row n1
    float cc[16], ssn[16];
    #pragma unroll
    for (int k = 0; k < 16; ++k)
      sincosf(THETA * (float)((k * t) & 255), &ssn[k], &cc[k]);
    float U[16], V[16];
    #pragma unroll
    for (int j = 0; j < 16; ++j) { U[j] = 0.f; V[j] = 0.f; }
    #pragma unroll
    for (int kk1 = 0; kk1 < 16; ++kk1) {
      float c = cc[kk1], s = ssn[kk1];
      #pragma unroll
      for (int j = 0; j < 16; ++j) {
        float r = rsm[kk1 * 16 + j];  // uniform addr -> broadcast, conflict-free
        U[j] = fmaf(c, r, U[j]);
        V[j] = fmaf(s, r, V[j]);
      }
    }
    float* __restrict__ wr = Wout + (size_t)blockIdx.x * 4128 + t * 32;
    #pragma unroll
    for (int j = 0; j < 16; ++j) {
      wr[j] = U[j] * INV_S;
      wr[16 + j] = V[j] * INV_S;
    }
  }
}

// -------------------------------------------------------------------------
// K3: inverse-DHT stage B. 2 blocks per (b,o); thread t = column n2.
// W rows arrive via SGPRs; per-lane twiddles in registers; row-pair symmetry
// gives 2 output rows per W row. Zero LDS.
// -------------------------------------------------------------------------
__global__ __launch_bounds__(256, 4) void k_invB(const float* __restrict__ Wb,
                                                 float* __restrict__ out) {
  const int t = threadIdx.x;
  const int img = blockIdx.x >> 1;
  const int half = blockIdx.x & 1;

  float cp[16], cm[16];
  #pragma unroll
  for (int k = 0; k < 16; ++k) {
    float s, c;
    sincosf(THETA * (float)((k * t) & 255), &s, &c);
    cp[k] = c + s;
    cm[k] = c - s;
  }

  const float* __restrict__ wbase = Wb + (size_t)img * 4128;
  float* __restrict__ op = out + (size_t)img * 65536 + t;

  const int n_lo = half ? 65 : 0;
  const int n_hi = half ? 128 : 64;
  for (int n = n_lo; n <= n_hi; ++n) {
    f32x16 uu, vv;
    sload2x16_64(wbase + n * 32, uu, vv);  // vv row at +0x40 bytes
    float a = 0.f, bsum = 0.f;
    #pragma unroll
    for (int k = 0; k < 16; ++k) {
      a = fmaf(uu[k], cp[k], a);        // v_fma with one SGPR operand
      bsum = fmaf(vv[k], cm[k], bsum);
    }
    op[(size_t)n * 256] = a + bsum;
    if (n >= 1 && n <= 127) op[(size_t)(256 - n) * 256] = a - bsum;
  }
}

extern "C" void kernel_launch(void* const* d_in, const int* in_sizes, int n_in,
                              void* d_out, int out_size, void* d_ws, size_t ws_size,
                              hipStream_t stream) {
  const float* x = (const float*)d_in[0];   // [16, 32, 256, 256] f32
  const float* w = (const float*)d_in[1];   // [32, 32, 16, 16]  f32
  float* out = (float*)d_out;               // [16, 32, 256, 256] f32

  float* TCb = (float*)d_ws;                // [256][16]  (16 KB)
  float* TSb = TCb + 4096;                  // [256][16]  (+0x4000 B from TCb)
  float* TPb = TSb + 4096;                  // [16][256]
  float* TMb = TPb + 4096;                  // [16][256]
  float* xh  = TMb + 4096;                  // [16*32][256]  (512 KB)
  float* Wb  = xh + 131072;                 // [512][129][32] (~8.5 MB; ws is 512 MB per round-1 fill counter)

  k_tab<<<1, 256, 0, stream>>>(TCb, TSb, TPb, TMb);
  k_fwd<<<16 * CI, 256, 0, stream>>>(x, TCb, TPb, TMb, xh);
  k_mid<<<16 * CO, 256, 0, stream>>>(xh, w, Wb);
  k_invB<<<2 * 16 * CO, 256, 0, stream>>>(Wb, out);
}

// Round 6
// 277.754 us; speedup vs baseline: 1.1107x; 1.1107x over previous
//
#include <hip/hip_runtime.h>

#define CI 32
#define CO 32

constexpr float INV_S = 1.0f / 256.0f;
constexpr float THETA = 6.28318530717958647692f / 256.0f;

// cos/sin(2*pi*k/256), k=0..15 — compile-time rotation constants (fold to
// SGPR-held literals inside unrolled FMAs; zero memory traffic).
__device__ constexpr float RC[16] = {
  1.0f,          0.9996988187f, 0.9987954562f, 0.9972904567f,
  0.9951847267f, 0.9924795346f, 0.9891765100f, 0.9852776424f,
  0.9807852804f, 0.9757021300f, 0.9700312532f, 0.9637760658f,
  0.9569403357f, 0.9495281806f, 0.9415440652f, 0.9329927988f};
__device__ constexpr float RS[16] = {
  0.0f,          0.0245412285f, 0.0490676743f, 0.0735645636f,
  0.0980171403f, 0.1224106752f, 0.1467304745f, 0.1709618888f,
  0.1950903220f, 0.2191012402f, 0.2429801799f, 0.2667127575f,
  0.2902846773f, 0.3136817404f, 0.3368898534f, 0.3598950365f};

// -------------------------------------------------------------------------
// K1: truncated forward DHT, one block per (b,i) image. Lane = column n2.
// Stage 1 contracts n1 with row-pair symmetry; twiddles are per-lane register
// state advanced by rotation (exact sincosf restart every 32 rows).
// Stage 2 contracts n2 with the same recurrence (exact restarts at n2=64q).
// -------------------------------------------------------------------------
__global__ __launch_bounds__(256, 2) void k_fwd(const float* __restrict__ x,
                                                float* __restrict__ xh) {
  __shared__ __align__(16) float C1[16][260];  // pad: k1-rows on distinct banks
  __shared__ __align__(16) float S1[16][260];
  const int t = threadIdx.x;
  const float* __restrict__ xp = x + (size_t)blockIdx.x * 65536 + t;

  float aC[16], aS[16];
  {  // rows 0 and 128: sin=0; cos row0 = 1, cos row128 = (-1)^k
    float x0 = xp[0];
    float xm = xp[128 * 256];
    float e = x0 + xm, o = x0 - xm;
    #pragma unroll
    for (int k = 0; k < 16; ++k) { aC[k] = (k & 1) ? o : e; aS[k] = 0.f; }
  }

  // twiddle state = (cos,sin)(THETA*k*n) at n=1
  float tc[16], ts[16];
  #pragma unroll
  for (int k = 0; k < 16; ++k) { tc[k] = RC[k]; ts[k] = RS[k]; }

  // software-pipelined x loads: 8 row-pairs per chunk, next chunk in flight
  float xl[8], xhb[8], nxl[8], nxh[8];
  #pragma unroll
  for (int j = 0; j < 8; ++j) {
    xl[j] = xp[(1 + j) * 256];
    xhb[j] = xp[(255 - j) * 256];
  }

  int n0 = 1;
  for (int c = 0; c < 15; ++c, n0 += 8) {
    if (c == 4 || c == 8 || c == 12) {  // exact restart: state at n = n0
      #pragma unroll
      for (int k = 0; k < 16; ++k)
        sincosf(THETA * (float)((n0 * k) & 255), &ts[k], &tc[k]);
    }
    if (c < 14) {
      #pragma unroll
      for (int j = 0; j < 8; ++j) {
        nxl[j] = xp[(n0 + 8 + j) * 256];
        nxh[j] = xp[(248 - n0 - j) * 256];  // 256-(n0+8+j)
      }
    } else {  // prefetch tail rows 121..127
      #pragma unroll
      for (int j = 0; j < 7; ++j) {
        nxl[j] = xp[(121 + j) * 256];
        nxh[j] = xp[(135 - j) * 256];
      }
    }
    #pragma unroll
    for (int j = 0; j < 8; ++j) {
      float es = xl[j] + xhb[j];
      float ds = xl[j] - xhb[j];
      #pragma unroll
      for (int k = 0; k < 16; ++k) {
        aC[k] = fmaf(es, tc[k], aC[k]);
        aS[k] = fmaf(ds, ts[k], aS[k]);
        float nc = fmaf(-ts[k], RS[k], tc[k] * RC[k]);  // rotate by THETA*k
        float ns = fmaf(tc[k], RS[k], ts[k] * RC[k]);
        tc[k] = nc; ts[k] = ns;
      }
    }
    #pragma unroll
    for (int j = 0; j < 8; ++j) { xl[j] = nxl[j]; xhb[j] = nxh[j]; }
  }
  // tail rows 121..127 (state is at n=121)
  #pragma unroll
  for (int j = 0; j < 7; ++j) {
    float es = xl[j] + xhb[j];
    float ds = xl[j] - xhb[j];
    #pragma unroll
    for (int k = 0; k < 16; ++k) {
      aC[k] = fmaf(es, tc[k], aC[k]);
      aS[k] = fmaf(ds, ts[k], aS[k]);
      float nc = fmaf(-ts[k], RS[k], tc[k] * RC[k]);
      float ns = fmaf(tc[k], RS[k], ts[k] * RC[k]);
      tc[k] = nc; ts[k] = ns;
    }
  }

  #pragma unroll
  for (int k = 0; k < 16; ++k) { C1[k][t] = aC[k]; S1[k][t] = aS[k]; }
  __syncthreads();

  // stage 2: Xh[k1,k2] = (1/256) sum_n2 [ C1*(c+s) + S1*(c-s) ],
  // (c,s) = trig(THETA*k2*n2) by per-lane recurrence, exact restart per 64.
  const int k1 = t >> 4, k2 = t & 15;
  float rc2, rs2;
  sincosf(THETA * (float)k2, &rs2, &rc2);  // per-lane rotation constant
  float acc = 0.f;
  #pragma unroll
  for (int q = 0; q < 4; ++q) {
    const int m = (q * k2) & 3;  // state at n2=64q: angle = (pi/2)*q*k2, exact
    float cc = (m == 0) ? 1.f : (m == 2) ? -1.f : 0.f;
    float ss = (m == 1) ? 1.f : (m == 3) ? -1.f : 0.f;
    #pragma unroll 2
    for (int n2 = q * 64; n2 < q * 64 + 64; n2 += 4) {
      float c4[4], s4[4];
      *(float4*)c4 = *(const float4*)&C1[k1][n2];
      *(float4*)s4 = *(const float4*)&S1[k1][n2];
      #pragma unroll
      for (int jj = 0; jj < 4; ++jj) {
        acc = fmaf(c4[jj], cc + ss, acc);
        acc = fmaf(s4[jj], cc - ss, acc);
        float nc = fmaf(-ss, rs2, cc * rc2);
        float ns = fmaf(cc, rs2, ss * rc2);
        cc = nc; ss = ns;
      }
    }
  }
  xh[(size_t)blockIdx.x * 256 + t] = acc * INV_S;
}

// -------------------------------------------------------------------------
// K2: mode mix + inverse-DHT stage A, one block per (b,o).
//   res = 0.5 * sum_i [ x*(w+wn) + xn*(w-wn) ],  n-index = (-k) mod 16
//   W[n1][j]    = sum_k1 res[k1][j]*cos(THETA*k1*n1)   (rows 0..128)
//   W[n1][16+j] = sum_k1 res[k1][j]*sin(THETA*k1*n1)
// Stage B: all 256 threads: (row = t&127, h = t>>7) does j = 8h..8h+7.
// -------------------------------------------------------------------------
__global__ __launch_bounds__(256, 2) void k_mid(const float* __restrict__ xh,
                                                const float* __restrict__ w,
                                                float* __restrict__ Wout) {
  __shared__ float xs[CI][256];
  __shared__ __align__(16) float rsm[256];
  const int t = threadIdx.x;
  const int b = blockIdx.x >> 5;
  const int o = blockIdx.x & 31;

  #pragma unroll 8
  for (int i = 0; i < CI; ++i)
    xs[i][t] = xh[(size_t)(b * CI + i) * 256 + t];
  __syncthreads();

  const int k1 = t >> 4, k2 = t & 15;
  const int tn = (((16 - k1) & 15) << 4) | ((16 - k2) & 15);
  float acc = 0.f;
  #pragma unroll 8
  for (int i = 0; i < CI; ++i) {
    const float* __restrict__ wrow = w + (size_t)(i * CO + o) * 256;
    float wp = wrow[t];
    float wn = wrow[tn];  // gather within 1 KB row: L1/L2 hit
    acc = fmaf(xs[i][t], wp + wn, acc);
    acc = fmaf(xs[i][tn], wp - wn, acc);
  }
  rsm[t] = 0.5f * acc;
  __syncthreads();

  const int row = t & 127, h = t >> 7;
  float cc[16], ss[16];
  #pragma unroll
  for (int k = 0; k < 16; ++k)
    sincosf(THETA * (float)((k * row) & 255), &ss[k], &cc[k]);
  float U[8], V[8];
  #pragma unroll
  for (int j = 0; j < 8; ++j) { U[j] = 0.f; V[j] = 0.f; }
  #pragma unroll
  for (int k = 0; k < 16; ++k) {
    float ra[8];
    *(float4*)&ra[0] = *(const float4*)&rsm[k * 16 + 8 * h];
    *(float4*)&ra[4] = *(const float4*)&rsm[k * 16 + 8 * h + 4];
    #pragma unroll
    for (int j = 0; j < 8; ++j) {
      U[j] = fmaf(cc[k], ra[j], U[j]);
      V[j] = fmaf(ss[k], ra[j], V[j]);
    }
  }
  float* __restrict__ wr = Wout + (size_t)blockIdx.x * 4160 + row * 32 + 8 * h;
  {
    float4 u0 = {U[0]*INV_S, U[1]*INV_S, U[2]*INV_S, U[3]*INV_S};
    float4 u1 = {U[4]*INV_S, U[5]*INV_S, U[6]*INV_S, U[7]*INV_S};
    float4 v0 = {V[0]*INV_S, V[1]*INV_S, V[2]*INV_S, V[3]*INV_S};
    float4 v1 = {V[4]*INV_S, V[5]*INV_S, V[6]*INV_S, V[7]*INV_S};
    *(float4*)&wr[0] = u0; *(float4*)&wr[4] = u1;
    *(float4*)&wr[16] = v0; *(float4*)&wr[20] = v1;
  }

  if (row == 0) {  // row 128: cos(pi*k1) = (-1)^k1, sin = 0
    float U8[8];
    #pragma unroll
    for (int j = 0; j < 8; ++j) U8[j] = 0.f;
    #pragma unroll
    for (int k = 0; k < 16; ++k) {
      float ra[8];
      *(float4*)&ra[0] = *(const float4*)&rsm[k * 16 + 8 * h];
      *(float4*)&ra[4] = *(const float4*)&rsm[k * 16 + 8 * h + 4];
      #pragma unroll
      for (int j = 0; j < 8; ++j)
        U8[j] = (k & 1) ? (U8[j] - ra[j]) : (U8[j] + ra[j]);
    }
    float* __restrict__ wr8 = Wout + (size_t)blockIdx.x * 4160 + 128 * 32 + 8 * h;
    float4 a0 = {U8[0]*INV_S, U8[1]*INV_S, U8[2]*INV_S, U8[3]*INV_S};
    float4 a1 = {U8[4]*INV_S, U8[5]*INV_S, U8[6]*INV_S, U8[7]*INV_S};
    float4 z = {0.f, 0.f, 0.f, 0.f};
    *(float4*)&wr8[0] = a0; *(float4*)&wr8[4] = a1;
    *(float4*)&wr8[16] = z; *(float4*)&wr8[20] = z;
  }
}

// -------------------------------------------------------------------------
// K3: inverse-DHT stage B. 2 blocks per (b,o); lane = column n2.
// W rows via pipelined uniform VMEM float4 loads (L2-hit); per-lane twiddles
// in registers; row-pair symmetry gives 2 output rows per W row. Zero LDS.
// -------------------------------------------------------------------------
__global__ __launch_bounds__(256, 4) void k_invB(const float* __restrict__ Wb,
                                                 float* __restrict__ out) {
  const int t = threadIdx.x;
  const int img = blockIdx.x >> 1;
  const int half = blockIdx.x & 1;

  float cp[16], cm[16];
  #pragma unroll
  for (int k = 0; k < 16; ++k) {
    float s, c;
    sincosf(THETA * (float)((k * t) & 255), &s, &c);
    cp[k] = c + s;
    cm[k] = c - s;
  }

  const float* __restrict__ wbase = Wb + (size_t)img * 4160;
  float* __restrict__ op = out + (size_t)img * 65536 + t;

  const int n_lo = half ? 65 : 0;
  const int n_hi = half ? 128 : 64;
  #pragma unroll 2
  for (int n = n_lo; n <= n_hi; ++n) {
    float uu[16], vv[16];
    #pragma unroll
    for (int q = 0; q < 4; ++q) {
      *(float4*)&uu[4 * q] = *(const float4*)(wbase + n * 32 + 4 * q);
      *(float4*)&vv[4 * q] = *(const float4*)(wbase + n * 32 + 16 + 4 * q);
    }
    float a = 0.f, bsum = 0.f;
    #pragma unroll
    for (int k = 0; k < 16; ++k) {
      a = fmaf(uu[k], cp[k], a);
      bsum = fmaf(vv[k], cm[k], bsum);
    }
    op[(size_t)n * 256] = a + bsum;
    if (n >= 1 && n <= 127) op[(size_t)(256 - n) * 256] = a - bsum;
  }
}

extern "C" void kernel_launch(void* const* d_in, const int* in_sizes, int n_in,
                              void* d_out, int out_size, void* d_ws, size_t ws_size,
                              hipStream_t stream) {
  const float* x = (const float*)d_in[0];   // [16, 32, 256, 256] f32
  const float* w = (const float*)d_in[1];   // [32, 32, 16, 16]  f32
  float* out = (float*)d_out;               // [16, 32, 256, 256] f32

  float* xhb = (float*)d_ws;                // [16*32][256]   (512 KB)
  float* Wb  = xhb + 131072;                // [512][130][32] (~8.5 MB)

  k_fwd<<<16 * CI, 256, 0, stream>>>(x, xhb);
  k_mid<<<16 * CO, 256, 0, stream>>>(xhb, w, Wb);
  k_invB<<<2 * 16 * CO, 256, 0, stream>>>(Wb, out);
}